// Round 8
// baseline (776.136 us; speedup 1.0000x reference)
//
#include <hip/hip_runtime.h>
#include <hip/hip_bf16.h>

typedef __bf16 bfx8 __attribute__((ext_vector_type(8)));
typedef __bf16 bfx4 __attribute__((ext_vector_type(4)));
typedef float  f32x4 __attribute__((ext_vector_type(4)));
typedef float  f32x16 __attribute__((ext_vector_type(16)));

#define MFMA16(a,b,c) __builtin_amdgcn_mfma_f32_16x16x32_bf16((a),(b),(c),0,0,0)
#define MFMA32(a,b,c) __builtin_amdgcn_mfma_f32_32x32x16_bf16((a),(b),(c),0,0,0)

// B=4, SM=1024, SI=4096, D=256, H=8, FF=1024
// External I/O: float32. Internal: bf16 operands + f32 accumulation.

// ---------------- merged attention-phase weight transposes (f32 -> bf16^T) ----------------
__global__ void trans_attn(const float* __restrict__ Wk, const float* __restrict__ Wv,
                           const float* __restrict__ Wq, const float* __restrict__ Wo,
                           __bf16* __restrict__ wkvqt, __bf16* __restrict__ wot) {
  int i = blockIdx.x * 256 + threadIdx.x;
  if (i < 65536) {                               // Wk [256][256]
    int r = i >> 8, c = i & 255;
    wkvqt[c * 256 + r] = (__bf16)Wk[i];
  } else if (i < 131072) {                       // Wv
    int e = i - 65536, r = e >> 8, c = e & 255;
    wkvqt[65536 + c * 256 + r] = (__bf16)Wv[e];
  } else if (i < 655360) {                       // Wq [8][256][256]
    int e = i - 131072, mat = e >> 16, rc = e & 65535, r = rc >> 8, c = rc & 255;
    wkvqt[131072 + mat * 65536 + c * 256 + r] = (__bf16)Wq[e];
  } else {                                       // Wo [2048][256]
    int e = i - 655360, r = e >> 8, c = e & 255;
    wot[c * 2048 + r] = (__bf16)Wo[e];
  }
}

// ---------------- merged FFN-phase weight transposes ----------------
__global__ void trans_ffn(const float* __restrict__ W_in, const float* __restrict__ Wg_nl,
                          const float* __restrict__ Wg_l, const float* __restrict__ Wg_o,
                          __bf16* __restrict__ dst) {
  int i = blockIdx.x * 256 + threadIdx.x;
  if (i < 262144) {                              // W_in [256][1024]
    int r = i >> 10, c = i & 1023;
    dst[c * 256 + r] = (__bf16)W_in[i];
  } else if (i < 1310720) {                      // Wg_nl [1024][1024]
    int e = i - 262144, r = e >> 10, c = e & 1023;
    dst[262144 + c * 1024 + r] = (__bf16)Wg_nl[e];
  } else if (i < 2359296) {                      // Wg_l
    int e = i - 1310720, r = e >> 10, c = e & 1023;
    dst[1310720 + c * 1024 + r] = (__bf16)Wg_l[e];
  } else {                                       // Wg_o [1024][256]
    int e = i - 2359296, r = e >> 8, c = e & 255;
    dst[2359296 + c * 1024 + r] = (__bf16)Wg_o[e];
  }
}

// ---------------- GEMM: C[M,N] = act(X[M,K] @ Wt[N,K]^T + bias) ----------------
// xmode: 0 bf16 X (row stride Kfull); 1 f32 X; 2 gated bf16 (stride 2048, x=a*b pairs k,k+1024)
// mode: 0 plain; 4 K|V split; 5 K|V|Q split; 6 dual-act (relu iff n<1024);
//       7 split-K f32 partials: Cf[z*M*N + m*N + n] (bias added in z==0 slice)
__global__ __launch_bounds__(256)
void gemm_bt(const __bf16* __restrict__ Xb, const float* __restrict__ Xf,
             const __bf16* __restrict__ Wt,
             const float* __restrict__ b1, const float* __restrict__ b2,
             const float* __restrict__ b3,
             __bf16* __restrict__ C, __bf16* __restrict__ C2, __bf16* __restrict__ C3,
             float* __restrict__ Cf,
             int M, int N, int Kfull, int kspan, int xmode, int mode, int act) {
  __shared__ __bf16 xs[128][72];
  __shared__ __bf16 wsm[128][72];

  const int tid  = threadIdx.x;
  const int lane = tid & 63;
  const int w    = tid >> 6;
  const int l15  = lane & 15;
  const int quad = lane >> 4;
  const int wm   = (w >> 1) * 64;
  const int wn   = (w & 1) * 64;
  const int m0   = blockIdx.x * 128;
  const int n0   = blockIdx.y * 128;
  const int k0   = (mode == 7) ? blockIdx.z * kspan : 0;

  f32x4 acc[4][4];
#pragma unroll
  for (int i = 0; i < 4; i++)
#pragma unroll
    for (int j = 0; j < 4; j++) acc[i][j] = (f32x4){0.f, 0.f, 0.f, 0.f};

  for (int kk = k0; kk < k0 + kspan; kk += 64) {
    __syncthreads();
#pragma unroll
    for (int rep = 0; rep < 4; rep++) {
      int idx = rep * 256 + tid;
      int row = idx >> 3;
      int g   = idx & 7;
      if (xmode == 1) {
        const float* p = Xf + (long)(m0 + row) * Kfull + kk + g * 8;
        f32x4 a0 = *(const f32x4*)p;
        f32x4 a1 = *(const f32x4*)(p + 4);
        bfx8 v;
#pragma unroll
        for (int j = 0; j < 4; j++) { v[j] = (__bf16)a0[j]; v[4 + j] = (__bf16)a1[j]; }
        *(bfx8*)&xs[row][g * 8] = v;
      } else if (xmode == 2) {
        const __bf16* p = Xb + (long)(m0 + row) * 2048 + kk + g * 8;
        bfx8 a = *(const bfx8*)p;
        bfx8 bb = *(const bfx8*)(p + 1024);
        bfx8 v;
#pragma unroll
        for (int j = 0; j < 8; j++) v[j] = (__bf16)((float)a[j] * (float)bb[j]);
        *(bfx8*)&xs[row][g * 8] = v;
      } else {
        *(bfx8*)&xs[row][g * 8] = *(const bfx8*)(Xb + (long)(m0 + row) * Kfull + kk + g * 8);
      }
      *(bfx8*)&wsm[row][g * 8] = *(const bfx8*)(Wt + (long)(n0 + row) * Kfull + kk + g * 8);
    }
    __syncthreads();
#pragma unroll
    for (int ks = 0; ks < 2; ks++) {
      bfx8 af[4], bf_[4];
#pragma unroll
      for (int i = 0; i < 4; i++) af[i]  = *(const bfx8*)&xs[wm + 16 * i + l15][ks * 32 + quad * 8];
#pragma unroll
      for (int j = 0; j < 4; j++) bf_[j] = *(const bfx8*)&wsm[wn + 16 * j + l15][ks * 32 + quad * 8];
#pragma unroll
      for (int i = 0; i < 4; i++)
#pragma unroll
        for (int j = 0; j < 4; j++) acc[i][j] = MFMA16(af[i], bf_[j], acc[i][j]);
    }
  }

#pragma unroll
  for (int j = 0; j < 4; j++) {
    int n = n0 + wn + 16 * j + l15;
    float bv;
    if (mode == 4)      bv = (n < 256) ? b1[n] : b2[n - 256];
    else if (mode == 5) bv = (n < 256) ? b1[n] : (n < 512) ? b2[n - 256] : b3[n - 512];
    else if (mode == 6) bv = (n < 1024) ? b1[n] : b2[n - 1024];
    else if (mode == 7) bv = (blockIdx.z == 0) ? b1[n] : 0.f;
    else                bv = b1[n];
#pragma unroll
    for (int i = 0; i < 4; i++) {
#pragma unroll
      for (int r = 0; r < 4; r++) {
        int m = m0 + wm + 16 * i + quad * 4 + r;   // C/D layout: row = quad*4+reg
        float v = acc[i][j][r] + bv;
        if (mode == 6) { if (n < 1024) v = fmaxf(v, 0.f); }
        else if (act == 1) v = fmaxf(v, 0.f);
        if (mode == 4) {
          if (n < 256) C[(long)m * 256 + n] = (__bf16)v;
          else {
            int bb_ = m >> 12, si = m & 4095;
            C2[((long)(bb_ * 128 + (si >> 5)) * 256 + (n - 256)) * 32 + (si & 31)] = (__bf16)v;
          }
        } else if (mode == 5) {
          if (n < 256)      C[(long)m * 256 + n] = (__bf16)v;
          else if (n < 512) C2[(long)m * 256 + (n - 256)] = (__bf16)v;
          else {
            int nn = n - 512, hh = nn >> 8, dd = nn & 255;
            C3[(long)hh * 1048576 + (long)m * 256 + dd] = (__bf16)v;
          }
        } else if (mode == 7) {
          Cf[(long)blockIdx.z * M * N + (long)m * N + n] = v;
        } else {
          C[(long)m * N + n] = (__bf16)v;
        }
      }
    }
  }
}

// ---------------- fused multi-query attention: direct-global frags, barrier-free K-loop ----
// grid (SM/64, B, H), block 256 (4 waves). Wave w: rg=w>>1 (rows mw..mw+31),
// sh=w&1 (key chunks sh*64..sh*64+63). Computes S^T = K Q^T per chunk (A=K, B=Q, frags
// loaded straight from global); P^T stays in registers, B-frag built via shfl_xor(32);
// O^T accumulated (A=V^T, B=P^T). One __syncthreads total (split-pair combine via LDS).
__global__ __launch_bounds__(256, 2)
void attn_kernel(const __bf16* __restrict__ qb,   // [H][B*SM][256]
                 const __bf16* __restrict__ ik,   // [B*SI][256]
                 const __bf16* __restrict__ ivT,  // [B][128][256][32]
                 const __bf16* __restrict__ mk,   // [B*SM][256]
                 const __bf16* __restrict__ mv,   // [B*SM][256]
                 __bf16* __restrict__ concat) {   // [B*SM][2048]
  __shared__ __bf16 comb[2][128][64];     // sh0 partial O (reg-layout), bf16  (32 KB)
  __shared__ float  comb_den[2][32];
  __shared__ __bf16 trans[2][32][264];    // O^T -> row-major transpose       (33 KB)

  const int tid  = threadIdx.x;
  const int lane = tid & 63;
  const int w    = tid >> 6;
  const int l31  = lane & 31;
  const int h    = lane >> 5;
  const int rg   = w >> 1;
  const int sh   = w & 1;

  const int m0 = blockIdx.x * 64;
  const int b  = blockIdx.y;
  const int hh = blockIdx.z;
  const int mw = m0 + rg * 32;

  const long qbase  = ((long)hh * 4096 + b * 1024 + mw) * 256;
  const long kvbase = (long)b * 4096 * 256;
  const long vtbase = (long)b * 128 * 8192;
  const long mbase  = ((long)b * 1024 + mw) * 256;

  // Q B-frags: lane (n=qrow=l31, h) holds Q[qrow][d = kt*16 + h*8 + j]
  bfx8 qbf[16];
  {
    const __bf16* qrow = qb + qbase + (long)l31 * 256 + h * 8;
#pragma unroll
    for (int kt = 0; kt < 16; kt++) qbf[kt] = *(const bfx8*)(qrow + kt * 16);
  }

  // self score for row l31 (each h half covers half the d's; xor-32 completes)
  float ps;
  {
    const __bf16* krow = mk + mbase + (long)l31 * 256 + h * 8;
    float s = 0.f;
#pragma unroll
    for (int kt = 0; kt < 16; kt++) {
      bfx8 kv = *(const bfx8*)(krow + kt * 16);
#pragma unroll
      for (int j = 0; j < 8; j++) s += (float)qbf[kt][j] * (float)kv[j];
    }
    s += __shfl_xor(s, 32);
    ps = __expf(fminf(s * 0.0625f, 30.f));
  }

  f32x16 oacc[8];
#pragma unroll
  for (int dt = 0; dt < 8; dt++)
#pragma unroll
    for (int i = 0; i < 16; i++) oacc[dt][i] = 0.f;
  float den = 0.f;

  for (int sc = sh * 64; sc < sh * 64 + 64; sc++) {
    // S^T = K Q^T : A-frag K[key=l31][d] contiguous from ik
    f32x16 sacc;
#pragma unroll
    for (int i = 0; i < 16; i++) sacc[i] = 0.f;
    const __bf16* krow = ik + kvbase + (long)(sc * 32 + l31) * 256 + h * 8;
#pragma unroll
    for (int kt = 0; kt < 16; kt++) {
      bfx8 kf = *(const bfx8*)(krow + kt * 16);
      sacc = MFMA32(kf, qbf[kt], sacc);
    }

    // P^T values: lane holds P^T[key=(r&3)+8*(r>>2)+4h][q=l31]
    float p[16];
#pragma unroll
    for (int r = 0; r < 16; r++) {
      p[r] = __expf(fminf(sacc[r] * 0.0625f, 30.f));
      den += p[r];
    }

    // build P^T B-frags (keys 0..15 and 16..31) via cross-half exchange
    bfx8 pf0, pf1;
#pragma unroll
    for (int j = 0; j < 4; j++) {
      float s0 = h ? p[j] : p[4 + j];
      float s1 = h ? p[8 + j] : p[12 + j];
      float r0 = __shfl_xor(s0, 32);
      float r1 = __shfl_xor(s1, 32);
      pf0[j]     = (__bf16)(h ? r0 : p[j]);
      pf0[4 + j] = (__bf16)(h ? p[4 + j] : r0);
      pf1[j]     = (__bf16)(h ? r1 : p[8 + j]);
      pf1[4 + j] = (__bf16)(h ? p[12 + j] : r1);
    }

    // O^T += V^T P^T : A-frag V^T[d=dt*32+l31][key] contiguous from ivT
    const __bf16* vrow = ivT + vtbase + (long)sc * 8192 + (long)l31 * 32 + h * 8;
#pragma unroll
    for (int dt = 0; dt < 8; dt++) {
      bfx8 a0 = *(const bfx8*)(vrow + dt * 1024);
      bfx8 a1 = *(const bfx8*)(vrow + dt * 1024 + 16);
      oacc[dt] = MFMA32(a0, pf0, oacc[dt]);
      oacc[dt] = MFMA32(a1, pf1, oacc[dt]);
    }
  }

  den += __shfl_xor(den, 32);   // combine key-halves held by h pairs

  if (sh == 0) {
#pragma unroll
    for (int dt = 0; dt < 8; dt++)
#pragma unroll
      for (int r = 0; r < 16; r++)
        comb[rg][dt * 16 + r][lane] = (__bf16)oacc[dt][r];
    if (h == 0) comb_den[rg][l31] = den;
  }
  __syncthreads();

  if (sh == 1) {
    float den_t = den + comb_den[rg][l31] + ps;
    float dinv  = 1.f / den_t;
    float psd   = ps * dinv;
    // normalized O^T -> row-major via LDS (same-wave write/read)
#pragma unroll
    for (int dt = 0; dt < 8; dt++)
#pragma unroll
      for (int r = 0; r < 16; r++) {
        float v = (oacc[dt][r] + (float)comb[rg][dt * 16 + r][lane]) * dinv;
        int drow = (r & 3) + 8 * (r >> 2) + 4 * h;
        trans[rg][l31][dt * 32 + drow] = (__bf16)v;
      }
    const __bf16* mvrow = mv + mbase + (long)l31 * 256 + h * 128;
    __bf16* crow = concat + ((long)(b * 1024 + mw + l31)) * 2048 + hh * 256 + h * 128;
#pragma unroll
    for (int k2 = 0; k2 < 16; k2++) {
      bfx8 tv  = *(const bfx8*)&trans[rg][l31][h * 128 + k2 * 8];
      bfx8 mvv = *(const bfx8*)(mvrow + k2 * 8);
      bfx8 ov;
#pragma unroll
      for (int j = 0; j < 8; j++) ov[j] = (__bf16)((float)tv[j] + psd * (float)mvv[j]);
      *(bfx8*)(crow + k2 * 8) = ov;
    }
  }
}

// ---------------- LayerNorm over 4 f32 partials + residual ----------------
__global__ __launch_bounds__(256)
void ln4_kernel(const float* __restrict__ parts, const float* __restrict__ res,
                const float* __restrict__ g, const float* __restrict__ beta,
                __bf16* __restrict__ outb, float* __restrict__ outf) {
  int row  = blockIdx.x * 4 + (threadIdx.x >> 6);
  int lane = threadIdx.x & 63;
  const float* p = parts + (long)row * 256 + lane * 4;
  f32x4 a0 = *(const f32x4*)p;
  f32x4 a1 = *(const f32x4*)(p + 1048576);
  f32x4 a2 = *(const f32x4*)(p + 2097152);
  f32x4 a3 = *(const f32x4*)(p + 3145728);
  f32x4 rv = *(const f32x4*)(res + (long)row * 256 + lane * 4);
  float v[4], s1 = 0.f, s2 = 0.f;
#pragma unroll
  for (int i = 0; i < 4; i++) {
    v[i] = a0[i] + a1[i] + a2[i] + a3[i] + rv[i];
    s1 += v[i];
    s2 += v[i] * v[i];
  }
#pragma unroll
  for (int off = 32; off >= 1; off >>= 1) {
    s1 += __shfl_xor(s1, off);
    s2 += __shfl_xor(s2, off);
  }
  float mean = s1 * (1.f / 256.f);
  float var  = fmaxf(s2 * (1.f / 256.f) - mean * mean, 0.f);
  float rstd = rsqrtf(var + 1e-6f);
#pragma unroll
  for (int i = 0; i < 4; i++) {
    int c = lane * 4 + i;
    float o = (v[i] - mean) * rstd * g[c] + beta[c];
    if (outb) outb[(long)row * 256 + c] = (__bf16)o;
    if (outf) outf[(long)row * 256 + c] = o;
  }
}

extern "C" void kernel_launch(void* const* d_in, const int* in_sizes, int n_in,
                              void* d_out, int out_size, void* d_ws, size_t ws_size,
                              hipStream_t stream) {
  const float* state  = (const float*)d_in[0];
  const float* input  = (const float*)d_in[1];
  const float* Wk     = (const float*)d_in[2];
  const float* bk     = (const float*)d_in[3];
  const float* Wv     = (const float*)d_in[4];
  const float* bv     = (const float*)d_in[5];
  const float* Wq     = (const float*)d_in[6];
  const float* bq     = (const float*)d_in[7];
  const float* Wo     = (const float*)d_in[8];
  const float* bo     = (const float*)d_in[9];
  const float* ln1g   = (const float*)d_in[10];
  const float* ln1b   = (const float*)d_in[11];
  const float* W_in   = (const float*)d_in[12];
  const float* b_in   = (const float*)d_in[13];
  const float* Wg_nl  = (const float*)d_in[14];
  const float* bg_nl  = (const float*)d_in[15];
  const float* Wg_l   = (const float*)d_in[16];
  const float* bg_l   = (const float*)d_in[17];
  const float* Wg_o   = (const float*)d_in[18];
  const float* bg_o   = (const float*)d_in[19];
  const float* ln2g   = (const float*)d_in[20];
  const float* ln2b   = (const float*)d_in[21];
  float* out = (float*)d_out;

  const size_t needed_elems = 28442624;   // 56.9 MB, proven budget
  if (ws_size < needed_elems * sizeof(__bf16)) return;

  __bf16* ws = (__bf16*)d_ws;
  size_t off = 0;
  auto alloc = [&](size_t n) { __bf16* p = ws + off; off += n; return p; };
  __bf16* Wkvqt  = alloc(655360);    // [2560][256]: Wk^T | Wv^T | Wq^T(8)
  __bf16* Wot    = alloc(524288);    // [256][2048]
  __bf16* ik     = alloc(4194304);   // [16384][256]
  __bf16* ivT    = alloc(4194304);   // [4][128][256][32]
  __bf16* mk     = alloc(1048576);   // [4096][256]
  __bf16* mv     = alloc(1048576);
  __bf16* qbuf   = alloc(8388608);   // [8][4096][256]
  __bf16* concat = alloc(8388608);   // [4096][2048]
  // FFN/late-phase aliases over dead buffers
  float*  wo_parts = (float*)qbuf;           // f32[4][4096][256] (qbuf dead after attn)
  __bf16* x      = mv;                       // bf16 LN1 out
  __bf16* hbuf   = ik;                       // [4096][1024]
  __bf16* t12    = qbuf;                     // [4096][2048]
  float*  ff_parts = (float*)ik;             // f32[4][4096][256] over ik+ivT
  __bf16* Wffn   = concat;                   // FFN weights^T (2621440 el)
  float*  xf     = (float*)(concat + 3670016); // f32 residual [4096][256]

  dim3 blk(256);

  trans_attn<<<dim3(4608), blk, 0, stream>>>(Wk, Wv, Wq, Wo, Wkvqt, Wot);

  // fused K|V input projection: N=512
  gemm_bt<<<dim3(128, 4), blk, 0, stream>>>(nullptr, input, Wkvqt, bk, bv, nullptr,
                                            ik, ivT, nullptr, nullptr,
                                            16384, 512, 256, 256, 1, 4, 0);
  // fused K|V|Q state projection: N=2560
  gemm_bt<<<dim3(32, 20), blk, 0, stream>>>(nullptr, state, Wkvqt, bk, bv, bq,
                                            mk, mv, qbuf, nullptr,
                                            4096, 2560, 256, 256, 1, 5, 0);

  attn_kernel<<<dim3(16, 4, 8), blk, 0, stream>>>(qbuf, ik, ivT, mk, mv, concat);

  // Wo: split-K (4 x 512) -> f32 partials, 256 blocks
  gemm_bt<<<dim3(32, 2, 4), blk, 0, stream>>>(concat, nullptr, Wot, bo, nullptr, nullptr,
                                              nullptr, nullptr, nullptr, wo_parts,
                                              4096, 256, 2048, 512, 0, 7, 0);
  ln4_kernel<<<dim3(1024), blk, 0, stream>>>(wo_parts, state, ln1g, ln1b, x, xf);

  trans_ffn<<<dim3(10240), blk, 0, stream>>>(W_in, Wg_nl, Wg_l, Wg_o, Wffn);

  gemm_bt<<<dim3(32, 8), blk, 0, stream>>>(x, nullptr, Wffn, b_in, nullptr, nullptr,
                                           hbuf, nullptr, nullptr, nullptr,
                                           4096, 1024, 256, 256, 0, 0, 1);
  // fused Wg_nl|Wg_l: N=2048, relu on first half
  gemm_bt<<<dim3(32, 16), blk, 0, stream>>>(hbuf, nullptr, Wffn + 262144, bg_nl, bg_l, nullptr,
                                            t12, nullptr, nullptr, nullptr,
                                            4096, 2048, 1024, 1024, 0, 6, 0);
  // Wg_o with gating fused into the stager: split-K (4 x 256) -> f32 partials
  gemm_bt<<<dim3(32, 2, 4), blk, 0, stream>>>(t12, nullptr, Wffn + 2359296, bg_o, nullptr, nullptr,
                                              nullptr, nullptr, nullptr, ff_parts,
                                              4096, 256, 1024, 256, 2, 7, 0);
  ln4_kernel<<<dim3(1024), blk, 0, stream>>>(ff_parts, xf, ln2g, ln2b, nullptr, out);
}

// Round 9
// 668.447 us; speedup vs baseline: 1.1611x; 1.1611x over previous
//
#include <hip/hip_runtime.h>
#include <hip/hip_bf16.h>

typedef __bf16 bfx8 __attribute__((ext_vector_type(8)));
typedef __bf16 bfx4 __attribute__((ext_vector_type(4)));
typedef float  f32x4 __attribute__((ext_vector_type(4)));
typedef float  f32x16 __attribute__((ext_vector_type(16)));

#define MFMA16(a,b,c) __builtin_amdgcn_mfma_f32_16x16x32_bf16((a),(b),(c),0,0,0)
#define MFMA32(a,b,c) __builtin_amdgcn_mfma_f32_32x32x16_bf16((a),(b),(c),0,0,0)

// B=4, SM=1024, SI=4096, D=256, H=8, FF=1024
// External I/O: float32. Internal: bf16 operands + f32 accumulation.

// ---------------- merged attention-phase weight transposes (f32 -> bf16^T) ----------------
__global__ void trans_attn(const float* __restrict__ Wk, const float* __restrict__ Wv,
                           const float* __restrict__ Wq, const float* __restrict__ Wo,
                           __bf16* __restrict__ wkvqt, __bf16* __restrict__ wot) {
  int i = blockIdx.x * 256 + threadIdx.x;
  if (i < 65536) {                               // Wk [256][256]
    int r = i >> 8, c = i & 255;
    wkvqt[c * 256 + r] = (__bf16)Wk[i];
  } else if (i < 131072) {                       // Wv
    int e = i - 65536, r = e >> 8, c = e & 255;
    wkvqt[65536 + c * 256 + r] = (__bf16)Wv[e];
  } else if (i < 655360) {                       // Wq [8][256][256]
    int e = i - 131072, mat = e >> 16, rc = e & 65535, r = rc >> 8, c = rc & 255;
    wkvqt[131072 + mat * 65536 + c * 256 + r] = (__bf16)Wq[e];
  } else {                                       // Wo [2048][256]
    int e = i - 655360, r = e >> 8, c = e & 255;
    wot[c * 2048 + r] = (__bf16)Wo[e];
  }
}

// ---------------- merged FFN-phase weight transposes ----------------
__global__ void trans_ffn(const float* __restrict__ W_in, const float* __restrict__ Wg_nl,
                          const float* __restrict__ Wg_l, const float* __restrict__ Wg_o,
                          __bf16* __restrict__ dst) {
  int i = blockIdx.x * 256 + threadIdx.x;
  if (i < 262144) {                              // W_in [256][1024]
    int r = i >> 10, c = i & 1023;
    dst[c * 256 + r] = (__bf16)W_in[i];
  } else if (i < 1310720) {                      // Wg_nl [1024][1024]
    int e = i - 262144, r = e >> 10, c = e & 1023;
    dst[262144 + c * 1024 + r] = (__bf16)Wg_nl[e];
  } else if (i < 2359296) {                      // Wg_l
    int e = i - 1310720, r = e >> 10, c = e & 1023;
    dst[1310720 + c * 1024 + r] = (__bf16)Wg_l[e];
  } else {                                       // Wg_o [1024][256]
    int e = i - 2359296, r = e >> 8, c = e & 255;
    dst[2359296 + c * 1024 + r] = (__bf16)Wg_o[e];
  }
}

// ---------------- GEMM: C[M,N] = act(X[M,K] @ Wt[N,K]^T + bias) ----------------
// xmode: 0 bf16 X (row stride Kfull); 1 f32 X; 2 gated bf16 (stride 2048, x=a*b pairs k,k+1024)
// mode: 0 plain; 4 K|V split; 5 K|V|Q split; 6 dual-act (relu iff n<1024);
//       7 split-K f32 partials: Cf[z*M*N + m*N + n] (bias added in z==0 slice)
__global__ __launch_bounds__(256)
void gemm_bt(const __bf16* __restrict__ Xb, const float* __restrict__ Xf,
             const __bf16* __restrict__ Wt,
             const float* __restrict__ b1, const float* __restrict__ b2,
             const float* __restrict__ b3,
             __bf16* __restrict__ C, __bf16* __restrict__ C2, __bf16* __restrict__ C3,
             float* __restrict__ Cf,
             int M, int N, int Kfull, int kspan, int xmode, int mode, int act) {
  __shared__ __bf16 xs[128][72];
  __shared__ __bf16 wsm[128][72];

  const int tid  = threadIdx.x;
  const int lane = tid & 63;
  const int w    = tid >> 6;
  const int l15  = lane & 15;
  const int quad = lane >> 4;
  const int wm   = (w >> 1) * 64;
  const int wn   = (w & 1) * 64;
  const int m0   = blockIdx.x * 128;
  const int n0   = blockIdx.y * 128;
  const int k0   = (mode == 7) ? blockIdx.z * kspan : 0;

  f32x4 acc[4][4];
#pragma unroll
  for (int i = 0; i < 4; i++)
#pragma unroll
    for (int j = 0; j < 4; j++) acc[i][j] = (f32x4){0.f, 0.f, 0.f, 0.f};

  for (int kk = k0; kk < k0 + kspan; kk += 64) {
    __syncthreads();
#pragma unroll
    for (int rep = 0; rep < 4; rep++) {
      int idx = rep * 256 + tid;
      int row = idx >> 3;
      int g   = idx & 7;
      if (xmode == 1) {
        const float* p = Xf + (long)(m0 + row) * Kfull + kk + g * 8;
        f32x4 a0 = *(const f32x4*)p;
        f32x4 a1 = *(const f32x4*)(p + 4);
        bfx8 v;
#pragma unroll
        for (int j = 0; j < 4; j++) { v[j] = (__bf16)a0[j]; v[4 + j] = (__bf16)a1[j]; }
        *(bfx8*)&xs[row][g * 8] = v;
      } else if (xmode == 2) {
        const __bf16* p = Xb + (long)(m0 + row) * 2048 + kk + g * 8;
        bfx8 a = *(const bfx8*)p;
        bfx8 bb = *(const bfx8*)(p + 1024);
        bfx8 v;
#pragma unroll
        for (int j = 0; j < 8; j++) v[j] = (__bf16)((float)a[j] * (float)bb[j]);
        *(bfx8*)&xs[row][g * 8] = v;
      } else {
        *(bfx8*)&xs[row][g * 8] = *(const bfx8*)(Xb + (long)(m0 + row) * Kfull + kk + g * 8);
      }
      *(bfx8*)&wsm[row][g * 8] = *(const bfx8*)(Wt + (long)(n0 + row) * Kfull + kk + g * 8);
    }
    __syncthreads();
#pragma unroll
    for (int ks = 0; ks < 2; ks++) {
      bfx8 af[4], bf_[4];
#pragma unroll
      for (int i = 0; i < 4; i++) af[i]  = *(const bfx8*)&xs[wm + 16 * i + l15][ks * 32 + quad * 8];
#pragma unroll
      for (int j = 0; j < 4; j++) bf_[j] = *(const bfx8*)&wsm[wn + 16 * j + l15][ks * 32 + quad * 8];
#pragma unroll
      for (int i = 0; i < 4; i++)
#pragma unroll
        for (int j = 0; j < 4; j++) acc[i][j] = MFMA16(af[i], bf_[j], acc[i][j]);
    }
  }

#pragma unroll
  for (int j = 0; j < 4; j++) {
    int n = n0 + wn + 16 * j + l15;
    float bv;
    if (mode == 4)      bv = (n < 256) ? b1[n] : b2[n - 256];
    else if (mode == 5) bv = (n < 256) ? b1[n] : (n < 512) ? b2[n - 256] : b3[n - 512];
    else if (mode == 6) bv = (n < 1024) ? b1[n] : b2[n - 1024];
    else if (mode == 7) bv = (blockIdx.z == 0) ? b1[n] : 0.f;
    else                bv = b1[n];
#pragma unroll
    for (int i = 0; i < 4; i++) {
#pragma unroll
      for (int r = 0; r < 4; r++) {
        int m = m0 + wm + 16 * i + quad * 4 + r;   // C/D layout: row = quad*4+reg
        float v = acc[i][j][r] + bv;
        if (mode == 6) { if (n < 1024) v = fmaxf(v, 0.f); }
        else if (act == 1) v = fmaxf(v, 0.f);
        if (mode == 4) {
          if (n < 256) C[(long)m * 256 + n] = (__bf16)v;
          else {
            int bb_ = m >> 12, si = m & 4095;
            C2[((long)(bb_ * 128 + (si >> 5)) * 256 + (n - 256)) * 32 + (si & 31)] = (__bf16)v;
          }
        } else if (mode == 5) {
          if (n < 256)      C[(long)m * 256 + n] = (__bf16)v;
          else if (n < 512) C2[(long)m * 256 + (n - 256)] = (__bf16)v;
          else {
            int nn = n - 512, hh = nn >> 8, dd = nn & 255;
            C3[(long)hh * 1048576 + (long)m * 256 + dd] = (__bf16)v;
          }
        } else if (mode == 7) {
          Cf[(long)blockIdx.z * M * N + (long)m * N + n] = v;
        } else {
          C[(long)m * N + n] = (__bf16)v;
        }
      }
    }
  }
}

// ---------------- fused multi-query attention: r7 datapath + key-parity split ----------------
// grid (SM/64, B, H) = 512 blocks, block 256 = 4 waves: rg=w>>1 (Q rows mw..mw+31),
// sh=w&1 (chunk parity; wave processes sc=2*it+sh, it=0..63). Both parities' K/V chunks
// staged in LDS each iteration; staging loads live in the barrier window (reg batches).
// sh partials combined once at the end via LDS (comb over dead lk region).
__global__ __launch_bounds__(256, 2)
void attn_kernel(const __bf16* __restrict__ qb,   // [H][B*SM][256]
                 const __bf16* __restrict__ ik,   // [B*SI][256]
                 const __bf16* __restrict__ ivT,  // [B][128][256][32]
                 const __bf16* __restrict__ mk,   // [B*SM][256]
                 const __bf16* __restrict__ mv,   // [B*SM][256]
                 __bf16* __restrict__ concat) {   // [B*SM][2048]
  __shared__ __bf16 lk[2][32][264];    // K chunks [parity][key][d], +8 pad   (33.8 KB)
  __shared__ __bf16 lvt[2][256][32];   // V^T chunks [parity][d][key], flat   (32 KB)
  __shared__ __bf16 lp[4][32][40];     // per-wave P tiles                    (10 KB)
  __shared__ float  cden[2][32];       // sh0 partial row denominators

  const int tid  = threadIdx.x;
  const int lane = tid & 63;
  const int w    = tid >> 6;
  const int l31  = lane & 31;
  const int h    = lane >> 5;
  const int rg   = w >> 1;
  const int sh   = w & 1;

  const int m0 = blockIdx.x * 64;
  const int b  = blockIdx.y;
  const int hh = blockIdx.z;
  const int mw = m0 + rg * 32;

  const long qbase  = ((long)hh * 4096 + b * 1024 + mw) * 256;
  const long kvbase = (long)b * 4096 * 256;
  const long vtbase = (long)b * 128 * 8192;
  const long mbase  = ((long)b * 1024 + mw) * 256;

  // Q A-frags: lane holds A[m=l31][k = kt*16 + h*8 + j]   (r7-proven mapping)
  bfx8 qf[16];
  {
    const __bf16* qrow = qb + qbase + (long)l31 * 256 + h * 8;
#pragma unroll
    for (int kt = 0; kt < 16; kt++) qf[kt] = *(const bfx8*)(qrow + kt * 16);
  }

  // self score for row l31 (halves hold complementary d-slices; xor-32 combines)
  float ps;
  {
    const __bf16* krow = mk + mbase + (long)l31 * 256 + h * 8;
    float s = 0.f;
#pragma unroll
    for (int kt = 0; kt < 16; kt++) {
      bfx8 kv = *(const bfx8*)(krow + kt * 16);
#pragma unroll
      for (int j = 0; j < 8; j++) s += (float)qf[kt][j] * (float)kv[j];
    }
    s += __shfl_xor(s, 32);
    ps = __expf(fminf(s * 0.0625f, 30.f));
  }

  bfx8 onesf;
#pragma unroll
  for (int j = 0; j < 8; j++) onesf[j] = (__bf16)1.0f;

  f32x16 oacc[8];
  f32x16 dacc;
#pragma unroll
  for (int i = 0; i < 16; i++) dacc[i] = 0.f;
#pragma unroll
  for (int dt = 0; dt < 8; dt++)
#pragma unroll
    for (int i = 0; i < 16; i++) oacc[dt][i] = 0.f;

  // prologue: stage chunk pair 0 (chunks 0,1)
#pragma unroll
  for (int p = 0; p < 2; p++)
#pragma unroll
    for (int rep = 0; rep < 4; rep++) {
      int idx = rep * 256 + tid;
      *(bfx8*)&lk[p][idx >> 5][(idx & 31) * 8] =
          *(const bfx8*)(ik + kvbase + (long)(p * 32 + (idx >> 5)) * 256 + (idx & 31) * 8);
      *(bfx8*)((__bf16*)lvt[p] + idx * 8) =
          *(const bfx8*)(ivT + vtbase + (long)p * 8192 + idx * 8);
    }
  __syncthreads();

  for (int it = 0; it < 64; it++) {
    // S = Q K^T from lk[sh]
    f32x16 sacc;
#pragma unroll
    for (int i = 0; i < 16; i++) sacc[i] = 0.f;
#pragma unroll
    for (int kt = 0; kt < 16; kt++) {
      bfx8 kf = *(const bfx8*)&lk[sh][l31][kt * 16 + h * 8];
      sacc = MFMA32(qf[kt], kf, sacc);
    }

    // P = exp(S/16) -> lp (C-layout rows; wave-private, same-wave DS order)
#pragma unroll
    for (int r = 0; r < 16; r++) {
      int row = (r & 3) + 8 * (r >> 2) + 4 * h;
      lp[w][row][l31] = (__bf16)__expf(fminf(sacc[r] * 0.0625f, 30.f));
    }

    // A-frags of P; den via ones-MFMA; O += P V from lvt[sh]
    bfx8 pf0 = *(const bfx8*)&lp[w][l31][h * 8];
    bfx8 pf1 = *(const bfx8*)&lp[w][l31][16 + h * 8];
    dacc = MFMA32(pf0, onesf, dacc);
    dacc = MFMA32(pf1, onesf, dacc);
#pragma unroll
    for (int dt = 0; dt < 8; dt++) {
      bfx8 vf0 = *(const bfx8*)&lvt[sh][dt * 32 + l31][h * 8];
      bfx8 vf1 = *(const bfx8*)&lvt[sh][dt * 32 + l31][16 + h * 8];
      oacc[dt] = MFMA32(pf0, vf0, oacc[dt]);
      oacc[dt] = MFMA32(pf1, vf1, oacc[dt]);
    }

    __syncthreads();                 // A: all lk/lvt reads of this pair done
    if (it < 63) {
      int nb = 2 * (it + 1);
      // K batch (regs -> LDS)
      bfx8 kr[8];
#pragma unroll
      for (int p = 0; p < 2; p++)
#pragma unroll
        for (int rep = 0; rep < 4; rep++) {
          int idx = rep * 256 + tid;
          kr[p * 4 + rep] = *(const bfx8*)(ik + kvbase +
              (long)((nb + p) * 32 + (idx >> 5)) * 256 + (idx & 31) * 8);
        }
#pragma unroll
      for (int p = 0; p < 2; p++)
#pragma unroll
        for (int rep = 0; rep < 4; rep++) {
          int idx = rep * 256 + tid;
          *(bfx8*)&lk[p][idx >> 5][(idx & 31) * 8] = kr[p * 4 + rep];
        }
      // V batch (regs -> LDS, reuses K batch's registers)
      bfx8 vr[8];
#pragma unroll
      for (int p = 0; p < 2; p++)
#pragma unroll
        for (int rep = 0; rep < 4; rep++) {
          int idx = rep * 256 + tid;
          vr[p * 4 + rep] = *(const bfx8*)(ivT + vtbase + (long)(nb + p) * 8192 + idx * 8);
        }
#pragma unroll
      for (int p = 0; p < 2; p++)
#pragma unroll
        for (int rep = 0; rep < 4; rep++) {
          int idx = rep * 256 + tid;
          *(bfx8*)((__bf16*)lvt[p] + idx * 8) = vr[p * 4 + rep];
        }
    }
    __syncthreads();                 // B: staged pair visible
  }

  // ---- combine sh partials, normalize, store ----
  __bf16* comb = &lk[0][0][0];       // reuse dead lk region (16,896 el; need 16,893)
  if (sh == 0) {
#pragma unroll
    for (int dt = 0; dt < 8; dt++)
#pragma unroll
      for (int r = 0; r < 16; r++)
        comb[(long)(rg * 128 + dt * 16 + r) * 66 + lane] = (__bf16)oacc[dt][r];
#pragma unroll
    for (int r = 0; r < 16; r++)
      if (l31 == 0) cden[rg][(r & 3) + 8 * (r >> 2) + 4 * h] = dacc[r];
  }
  __syncthreads();
  if (sh == 1) {
#pragma unroll
    for (int r = 0; r < 16; r++) {
      int row = (r & 3) + 8 * (r >> 2) + 4 * h;
      float psr  = __shfl(ps, row);
      float dinv = 1.f / (dacc[r] + cden[rg][row] + psr);
      const __bf16* mvrow = mv + mbase + (long)row * 256;
      __bf16* crow = concat + ((long)(b * 1024 + mw + row)) * 2048 + hh * 256;
#pragma unroll
      for (int dt = 0; dt < 8; dt++) {
        int d = dt * 32 + l31;
        float v = (oacc[dt][r] + (float)comb[(long)(rg * 128 + dt * 16 + r) * 66 + lane]
                   + psr * (float)mvrow[d]) * dinv;
        crow[d] = (__bf16)v;
      }
    }
  }
}

// ---------------- LayerNorm over 4 f32 partials + residual ----------------
__global__ __launch_bounds__(256)
void ln4_kernel(const float* __restrict__ parts, const float* __restrict__ res,
                const float* __restrict__ g, const float* __restrict__ beta,
                __bf16* __restrict__ outb, float* __restrict__ outf) {
  int row  = blockIdx.x * 4 + (threadIdx.x >> 6);
  int lane = threadIdx.x & 63;
  const float* p = parts + (long)row * 256 + lane * 4;
  f32x4 a0 = *(const f32x4*)p;
  f32x4 a1 = *(const f32x4*)(p + 1048576);
  f32x4 a2 = *(const f32x4*)(p + 2097152);
  f32x4 a3 = *(const f32x4*)(p + 3145728);
  f32x4 rv = *(const f32x4*)(res + (long)row * 256 + lane * 4);
  float v[4], s1 = 0.f, s2 = 0.f;
#pragma unroll
  for (int i = 0; i < 4; i++) {
    v[i] = a0[i] + a1[i] + a2[i] + a3[i] + rv[i];
    s1 += v[i];
    s2 += v[i] * v[i];
  }
#pragma unroll
  for (int off = 32; off >= 1; off >>= 1) {
    s1 += __shfl_xor(s1, off);
    s2 += __shfl_xor(s2, off);
  }
  float mean = s1 * (1.f / 256.f);
  float var  = fmaxf(s2 * (1.f / 256.f) - mean * mean, 0.f);
  float rstd = rsqrtf(var + 1e-6f);
#pragma unroll
  for (int i = 0; i < 4; i++) {
    int c = lane * 4 + i;
    float o = (v[i] - mean) * rstd * g[c] + beta[c];
    if (outb) outb[(long)row * 256 + c] = (__bf16)o;
    if (outf) outf[(long)row * 256 + c] = o;
  }
}

extern "C" void kernel_launch(void* const* d_in, const int* in_sizes, int n_in,
                              void* d_out, int out_size, void* d_ws, size_t ws_size,
                              hipStream_t stream) {
  const float* state  = (const float*)d_in[0];
  const float* input  = (const float*)d_in[1];
  const float* Wk     = (const float*)d_in[2];
  const float* bk     = (const float*)d_in[3];
  const float* Wv     = (const float*)d_in[4];
  const float* bv     = (const float*)d_in[5];
  const float* Wq     = (const float*)d_in[6];
  const float* bq     = (const float*)d_in[7];
  const float* Wo     = (const float*)d_in[8];
  const float* bo     = (const float*)d_in[9];
  const float* ln1g   = (const float*)d_in[10];
  const float* ln1b   = (const float*)d_in[11];
  const float* W_in   = (const float*)d_in[12];
  const float* b_in   = (const float*)d_in[13];
  const float* Wg_nl  = (const float*)d_in[14];
  const float* bg_nl  = (const float*)d_in[15];
  const float* Wg_l   = (const float*)d_in[16];
  const float* bg_l   = (const float*)d_in[17];
  const float* Wg_o   = (const float*)d_in[18];
  const float* bg_o   = (const float*)d_in[19];
  const float* ln2g   = (const float*)d_in[20];
  const float* ln2b   = (const float*)d_in[21];
  float* out = (float*)d_out;

  const size_t needed_elems = 28442624;   // 56.9 MB, proven budget
  if (ws_size < needed_elems * sizeof(__bf16)) return;

  __bf16* ws = (__bf16*)d_ws;
  size_t off = 0;
  auto alloc = [&](size_t n) { __bf16* p = ws + off; off += n; return p; };
  __bf16* Wkvqt  = alloc(655360);    // [2560][256]: Wk^T | Wv^T | Wq^T(8)
  __bf16* Wot    = alloc(524288);    // [256][2048]
  __bf16* ik     = alloc(4194304);   // [16384][256]
  __bf16* ivT    = alloc(4194304);   // [4][128][256][32]
  __bf16* mk     = alloc(1048576);   // [4096][256]
  __bf16* mv     = alloc(1048576);
  __bf16* qbuf   = alloc(8388608);   // [8][4096][256]
  __bf16* concat = alloc(8388608);   // [4096][2048]
  // FFN/late-phase aliases over dead buffers
  float*  wo_parts = (float*)qbuf;           // f32[4][4096][256] (qbuf dead after attn)
  __bf16* x      = mv;                       // bf16 LN1 out
  __bf16* hbuf   = ik;                       // [4096][1024]
  __bf16* t12    = qbuf;                     // [4096][2048]
  float*  ff_parts = (float*)ik;             // f32[4][4096][256] over ik+ivT
  __bf16* Wffn   = concat;                   // FFN weights^T (2621440 el)
  float*  xf     = (float*)(concat + 3670016); // f32 residual [4096][256]

  dim3 blk(256);

  trans_attn<<<dim3(4608), blk, 0, stream>>>(Wk, Wv, Wq, Wo, Wkvqt, Wot);

  // fused K|V input projection: N=512
  gemm_bt<<<dim3(128, 4), blk, 0, stream>>>(nullptr, input, Wkvqt, bk, bv, nullptr,
                                            ik, ivT, nullptr, nullptr,
                                            16384, 512, 256, 256, 1, 4, 0);
  // fused K|V|Q state projection: N=2560
  gemm_bt<<<dim3(32, 20), blk, 0, stream>>>(nullptr, state, Wkvqt, bk, bv, bq,
                                            mk, mv, qbuf, nullptr,
                                            4096, 2560, 256, 256, 1, 5, 0);

  attn_kernel<<<dim3(16, 4, 8), blk, 0, stream>>>(qbuf, ik, ivT, mk, mv, concat);

  // Wo: split-K (4 x 512) -> f32 partials, 256 blocks
  gemm_bt<<<dim3(32, 2, 4), blk, 0, stream>>>(concat, nullptr, Wot, bo, nullptr, nullptr,
                                              nullptr, nullptr, nullptr, wo_parts,
                                              4096, 256, 2048, 512, 0, 7, 0);
  ln4_kernel<<<dim3(1024), blk, 0, stream>>>(wo_parts, state, ln1g, ln1b, x, xf);

  trans_ffn<<<dim3(10240), blk, 0, stream>>>(W_in, Wg_nl, Wg_l, Wg_o, Wffn);

  gemm_bt<<<dim3(32, 8), blk, 0, stream>>>(x, nullptr, Wffn, b_in, nullptr, nullptr,
                                           hbuf, nullptr, nullptr, nullptr,
                                           4096, 1024, 256, 256, 0, 0, 1);
  // fused Wg_nl|Wg_l: N=2048, relu on first half
  gemm_bt<<<dim3(32, 16), blk, 0, stream>>>(hbuf, nullptr, Wffn + 262144, bg_nl, bg_l, nullptr,
                                            t12, nullptr, nullptr, nullptr,
                                            4096, 2048, 1024, 1024, 0, 6, 0);
  // Wg_o with gating fused into the stager: split-K (4 x 256) -> f32 partials
  gemm_bt<<<dim3(32, 2, 4), blk, 0, stream>>>(t12, nullptr, Wffn + 2359296, bg_o, nullptr, nullptr,
                                              nullptr, nullptr, nullptr, ff_parts,
                                              4096, 256, 1024, 256, 2, 7, 0);
  ln4_kernel<<<dim3(1024), blk, 0, stream>>>(ff_parts, xf, ln2g, ln2b, nullptr, out);
}

// Round 10
// 488.369 us; speedup vs baseline: 1.5892x; 1.3687x over previous
//
#include <hip/hip_runtime.h>
#include <hip/hip_bf16.h>

typedef __bf16 bfx8 __attribute__((ext_vector_type(8)));
typedef __bf16 bfx4 __attribute__((ext_vector_type(4)));
typedef float  f32x4 __attribute__((ext_vector_type(4)));
typedef float  f32x16 __attribute__((ext_vector_type(16)));

#define MFMA16(a,b,c) __builtin_amdgcn_mfma_f32_16x16x32_bf16((a),(b),(c),0,0,0)
#define MFMA32(a,b,c) __builtin_amdgcn_mfma_f32_32x32x16_bf16((a),(b),(c),0,0,0)

// B=4, SM=1024, SI=4096, D=256, H=8, FF=1024
// External I/O: float32. Internal: bf16 operands + f32 accumulation.

// ---------------- coalesced 64x64 tile transpose (f32 -> bf16^T) ----------------
__device__ __forceinline__ void tile_tr(const float* __restrict__ src, __bf16* __restrict__ dst,
                                        int R, int C, int tile, float (*lt)[65]) {
  int tpr = C >> 6;
  int tr = tile / tpr, tc = tile % tpr;
  int c  = threadIdx.x & 63;
  int r0 = (threadIdx.x >> 6) << 4;
  const float* sp = src + (long)(tr * 64 + r0) * C + tc * 64 + c;
#pragma unroll
  for (int i = 0; i < 16; i++) lt[r0 + i][c] = sp[(long)i * C];
  __syncthreads();
  __bf16* dp = dst + (long)(tc * 64 + r0) * R + tr * 64 + c;
#pragma unroll
  for (int i = 0; i < 16; i++) dp[(long)i * R] = (__bf16)lt[c][r0 + i];
}

__global__ void trans_attn_t(const float* __restrict__ Wk, const float* __restrict__ Wv,
                             const float* __restrict__ Wq, const float* __restrict__ Wo,
                             __bf16* __restrict__ wkvqt, __bf16* __restrict__ wot) {
  __shared__ float lt[64][65];
  int t = blockIdx.x;
  if (t < 16)       tile_tr(Wk, wkvqt, 256, 256, t, lt);
  else if (t < 32)  tile_tr(Wv, wkvqt + 65536, 256, 256, t - 16, lt);
  else if (t < 160) {
    int e = t - 32, m = e >> 4;
    tile_tr(Wq + (long)m * 65536, wkvqt + 131072 + (long)m * 65536, 256, 256, e & 15, lt);
  } else            tile_tr(Wo, wot, 2048, 256, t - 160, lt);
}

__global__ void trans_ffn_t(const float* __restrict__ W_in, const float* __restrict__ Wg_nl,
                            const float* __restrict__ Wg_l, const float* __restrict__ Wg_o,
                            __bf16* __restrict__ dst) {
  __shared__ float lt[64][65];
  int t = blockIdx.x;
  if (t < 64)       tile_tr(W_in, dst, 256, 1024, t, lt);
  else if (t < 320) tile_tr(Wg_nl, dst + 262144, 1024, 1024, t - 64, lt);
  else if (t < 576) tile_tr(Wg_l, dst + 1310720, 1024, 1024, t - 320, lt);
  else              tile_tr(Wg_o, dst + 2359296, 1024, 256, t - 576, lt);
}

// ---------------- GEMM body: C[M,N] = act(X[M,K] @ Wt[N,K]^T + bias) ----------------
// xmode: 0 bf16 X (row stride Kfull); 1 f32 X; 2 gated bf16 (stride 2048, x=a*b pairs k,k+1024)
// mode: 0 plain; 4 K|V split; 5 K|V|Q split; 6 dual-act (relu iff n<1024);
//       7 split-K f32 partials: Cf[z*M*N + m*N + n] (bias added in z==0 slice)
__device__ __forceinline__
void gemm_body(const __bf16* __restrict__ Xb, const float* __restrict__ Xf,
               const __bf16* __restrict__ Wt,
               const float* __restrict__ b1, const float* __restrict__ b2,
               const float* __restrict__ b3,
               __bf16* __restrict__ C, __bf16* __restrict__ C2, __bf16* __restrict__ C3,
               float* __restrict__ Cf,
               int M, int N, int Kfull, int kspan, int xmode, int mode, int act,
               int bx, int by, int bz, __bf16* xs, __bf16* wsm) {
  const int tid  = threadIdx.x;
  const int lane = tid & 63;
  const int w    = tid >> 6;
  const int l15  = lane & 15;
  const int quad = lane >> 4;
  const int wm   = (w >> 1) * 64;
  const int wn   = (w & 1) * 64;
  const int m0   = bx * 128;
  const int n0   = by * 128;
  const int k0   = (mode == 7) ? bz * kspan : 0;

  f32x4 acc[4][4];
#pragma unroll
  for (int i = 0; i < 4; i++)
#pragma unroll
    for (int j = 0; j < 4; j++) acc[i][j] = (f32x4){0.f, 0.f, 0.f, 0.f};

  for (int kk = k0; kk < k0 + kspan; kk += 64) {
    __syncthreads();
#pragma unroll
    for (int rep = 0; rep < 4; rep++) {
      int idx = rep * 256 + tid;
      int row = idx >> 3;
      int g   = idx & 7;
      if (xmode == 1) {
        const float* p = Xf + (long)(m0 + row) * Kfull + kk + g * 8;
        f32x4 a0 = *(const f32x4*)p;
        f32x4 a1 = *(const f32x4*)(p + 4);
        bfx8 v;
#pragma unroll
        for (int j = 0; j < 4; j++) { v[j] = (__bf16)a0[j]; v[4 + j] = (__bf16)a1[j]; }
        *(bfx8*)&xs[row * 72 + g * 8] = v;
      } else if (xmode == 2) {
        const __bf16* p = Xb + (long)(m0 + row) * 2048 + kk + g * 8;
        bfx8 a = *(const bfx8*)p;
        bfx8 bb = *(const bfx8*)(p + 1024);
        bfx8 v;
#pragma unroll
        for (int j = 0; j < 8; j++) v[j] = (__bf16)((float)a[j] * (float)bb[j]);
        *(bfx8*)&xs[row * 72 + g * 8] = v;
      } else {
        *(bfx8*)&xs[row * 72 + g * 8] = *(const bfx8*)(Xb + (long)(m0 + row) * Kfull + kk + g * 8);
      }
      *(bfx8*)&wsm[row * 72 + g * 8] = *(const bfx8*)(Wt + (long)(n0 + row) * Kfull + kk + g * 8);
    }
    __syncthreads();
#pragma unroll
    for (int ks = 0; ks < 2; ks++) {
      bfx8 af[4], bf_[4];
#pragma unroll
      for (int i = 0; i < 4; i++) af[i]  = *(const bfx8*)&xs[(wm + 16 * i + l15) * 72 + ks * 32 + quad * 8];
#pragma unroll
      for (int j = 0; j < 4; j++) bf_[j] = *(const bfx8*)&wsm[(wn + 16 * j + l15) * 72 + ks * 32 + quad * 8];
#pragma unroll
      for (int i = 0; i < 4; i++)
#pragma unroll
        for (int j = 0; j < 4; j++) acc[i][j] = MFMA16(af[i], bf_[j], acc[i][j]);
    }
  }

#pragma unroll
  for (int j = 0; j < 4; j++) {
    int n = n0 + wn + 16 * j + l15;
    float bv;
    if (mode == 4)      bv = (n < 256) ? b1[n] : b2[n - 256];
    else if (mode == 5) bv = (n < 256) ? b1[n] : (n < 512) ? b2[n - 256] : b3[n - 512];
    else if (mode == 6) bv = (n < 1024) ? b1[n] : b2[n - 1024];
    else if (mode == 7) bv = (bz == 0) ? b1[n] : 0.f;
    else                bv = b1[n];
#pragma unroll
    for (int i = 0; i < 4; i++) {
#pragma unroll
      for (int r = 0; r < 4; r++) {
        int m = m0 + wm + 16 * i + quad * 4 + r;   // C/D layout: row = quad*4+reg
        float v = acc[i][j][r] + bv;
        if (mode == 6) { if (n < 1024) v = fmaxf(v, 0.f); }
        else if (act == 1) v = fmaxf(v, 0.f);
        if (mode == 4) {
          if (n < 256) C[(long)m * 256 + n] = (__bf16)v;
          else {
            int bb_ = m >> 12, si = m & 4095;
            C2[((long)(bb_ * 128 + (si >> 5)) * 256 + (n - 256)) * 32 + (si & 31)] = (__bf16)v;
          }
        } else if (mode == 5) {
          if (n < 256)      C[(long)m * 256 + n] = (__bf16)v;
          else if (n < 512) C2[(long)m * 256 + (n - 256)] = (__bf16)v;
          else {
            int nn = n - 512, hh = nn >> 8, dd = nn & 255;
            C3[(long)hh * 1048576 + (long)m * 256 + dd] = (__bf16)v;
          }
        } else if (mode == 7) {
          Cf[(long)bz * M * N + (long)m * N + n] = v;
        } else {
          C[(long)m * N + n] = (__bf16)v;
        }
      }
    }
  }
}

__global__ __launch_bounds__(256)
void gemm_bt(const __bf16* Xb, const float* Xf, const __bf16* Wt,
             const float* b1, const float* b2, const float* b3,
             __bf16* C, __bf16* C2, __bf16* C3, float* Cf,
             int M, int N, int Kfull, int kspan, int xmode, int mode, int act) {
  __shared__ __bf16 xs[128 * 72];
  __shared__ __bf16 wsm[128 * 72];
  gemm_body(Xb, Xf, Wt, b1, b2, b3, C, C2, C3, Cf, M, N, Kfull, kspan, xmode, mode, act,
            blockIdx.x, blockIdx.y, blockIdx.z, xs, wsm);
}

// merged K|V input projection (blocks 0..511, grid (128,4)) + K|V|Q state projection
// (blocks 512..1151, grid (32,20)) — both depend only on trans_attn_t.
__global__ __launch_bounds__(256)
void proj2(const float* input, const float* state, const __bf16* Wkvqt,
           const float* bk, const float* bv, const float* bq,
           __bf16* ik, __bf16* ivT, __bf16* mk, __bf16* mv, __bf16* qbuf) {
  __shared__ __bf16 xs[128 * 72];
  __shared__ __bf16 wsm[128 * 72];
  int bid = blockIdx.x;
  if (bid < 512) {
    gemm_body(nullptr, input, Wkvqt, bk, bv, nullptr, ik, ivT, nullptr, nullptr,
              16384, 512, 256, 256, 1, 4, 0, bid & 127, bid >> 7, 0, xs, wsm);
  } else {
    int b2 = bid - 512;
    gemm_body(nullptr, state, Wkvqt, bk, bv, bq, mk, mv, qbuf, nullptr,
              4096, 2560, 256, 256, 1, 5, 0, b2 & 31, b2 >> 5, 0, xs, wsm);
  }
}

// ---------------- fused multi-query attention (r7 datapath, single barrier/chunk) --------
// grid (SM/128, B, H) = 256 blocks, 4 waves; wave w owns Q rows w*32..w*32+31.
// Full double-buffer (lk AND lvt): loads at loop top (covered by compute), stores to
// alternate buffers after all reads, ONE __syncthreads per chunk.
__global__ __launch_bounds__(256)
void attn_kernel(const __bf16* __restrict__ qb,   // [H][B*SM][256]
                 const __bf16* __restrict__ ik,   // [B*SI][256]
                 const __bf16* __restrict__ ivT,  // [B][128][256][32]
                 const __bf16* __restrict__ mk,   // [B*SM][256]
                 const __bf16* __restrict__ mv,   // [B*SM][256]
                 __bf16* __restrict__ concat) {   // [B*SM][2048]
  __shared__ __bf16 lk[2][32][264];     // K chunks [buf][key][d], +8 pad     (33.8 KB)
  __shared__ __bf16 lvt[2][256][40];    // V^T chunks [buf][d][key], +8 pad   (40 KB)
  __shared__ __bf16 lp[128][40];        // P tiles, 32 rows/wave              (10 KB)

  const int tid  = threadIdx.x;
  const int lane = tid & 63;
  const int w    = tid >> 6;
  const int l31  = lane & 31;
  const int h    = lane >> 5;

  const int m0 = blockIdx.x * 128;
  const int b  = blockIdx.y;
  const int hh = blockIdx.z;
  const int mw = m0 + w * 32;

  const long qbase  = ((long)hh * 4096 + b * 1024 + mw) * 256;
  const long kvbase = (long)b * 4096 * 256;
  const long vtbase = (long)b * 128 * 8192;
  const long mbase  = ((long)b * 1024 + mw) * 256;

  // Q A-frags: lane holds A[m=l31][k = kt*16 + h*8 + j]
  bfx8 qf[16];
  {
    const __bf16* qrow = qb + qbase + (long)l31 * 256 + h * 8;
#pragma unroll
    for (int kt = 0; kt < 16; kt++) qf[kt] = *(const bfx8*)(qrow + kt * 16);
  }

  // self score for row l31 (halves hold complementary d-slices; xor-32 combines)
  float ps_l;
  {
    const __bf16* krow = mk + mbase + (long)l31 * 256 + h * 8;
    float s = 0.f;
#pragma unroll
    for (int kt = 0; kt < 16; kt++) {
      bfx8 kv = *(const bfx8*)(krow + kt * 16);
#pragma unroll
      for (int j = 0; j < 8; j++) s += (float)qf[kt][j] * (float)kv[j];
    }
    s += __shfl_xor(s, 32);
    ps_l = __expf(fminf(s * 0.0625f, 30.f));
  }

  bfx8 onesf;
#pragma unroll
  for (int j = 0; j < 8; j++) onesf[j] = (__bf16)1.0f;

  f32x16 oacc[8];
  f32x16 dacc;
#pragma unroll
  for (int i = 0; i < 16; i++) dacc[i] = 0.f;
#pragma unroll
  for (int dt = 0; dt < 8; dt++)
#pragma unroll
    for (int i = 0; i < 16; i++) oacc[dt][i] = 0.f;

  // prologue: stage chunk 0 into buffer 0
#pragma unroll
  for (int rep = 0; rep < 4; rep++) {
    int idx = rep * 256 + tid;
    *(bfx8*)&lk[0][idx >> 5][(idx & 31) * 8] =
        *(const bfx8*)(ik + kvbase + (long)(idx >> 5) * 256 + (idx & 31) * 8);
    *(bfx8*)&lvt[0][idx >> 2][(idx & 3) * 8] = *(const bfx8*)(ivT + vtbase + (long)idx * 8);
  }
  __syncthreads();

  for (int sc = 0; sc < 128; sc++) {
    const int cur = sc & 1;
    bfx8 kreg[4], vreg[4];
    if (sc < 127) {               // loads at loop top — covered by full chunk compute
      const long kb = kvbase + (long)(sc + 1) * 8192;
      const long vb = vtbase + (long)(sc + 1) * 8192;
#pragma unroll
      for (int rep = 0; rep < 4; rep++) {
        int idx = rep * 256 + tid;
        kreg[rep] = *(const bfx8*)(ik + kb + (long)(idx >> 5) * 256 + (idx & 31) * 8);
        vreg[rep] = *(const bfx8*)(ivT + vb + (long)idx * 8);
      }
    }

    // S = Q K^T from lk[cur]
    f32x16 sacc;
#pragma unroll
    for (int i = 0; i < 16; i++) sacc[i] = 0.f;
#pragma unroll
    for (int kt = 0; kt < 16; kt++) {
      bfx8 kf = *(const bfx8*)&lk[cur][l31][kt * 16 + h * 8];
      sacc = MFMA32(qf[kt], kf, sacc);
    }

    // P = exp(S/16) -> lp (C-layout rows; wave-private, same-wave DS order)
#pragma unroll
    for (int r = 0; r < 16; r++) {
      int row = (r & 3) + 8 * (r >> 2) + 4 * h;
      lp[w * 32 + row][l31] = (__bf16)__expf(fminf(sacc[r] * 0.0625f, 30.f));
    }

    // A-frags of P; den via ones-MFMA; O += P V from lvt[cur]
    bfx8 pf0 = *(const bfx8*)&lp[w * 32 + l31][h * 8];
    bfx8 pf1 = *(const bfx8*)&lp[w * 32 + l31][16 + h * 8];
    dacc = MFMA32(pf0, onesf, dacc);
    dacc = MFMA32(pf1, onesf, dacc);
#pragma unroll
    for (int dt = 0; dt < 8; dt++) {
      bfx8 vf0 = *(const bfx8*)&lvt[cur][dt * 32 + l31][h * 8];
      bfx8 vf1 = *(const bfx8*)&lvt[cur][dt * 32 + l31][16 + h * 8];
      oacc[dt] = MFMA32(pf0, vf0, oacc[dt]);
      oacc[dt] = MFMA32(pf1, vf1, oacc[dt]);
    }

    // stores to the ALTERNATE buffers — no reader conflict, no pre-store barrier
    if (sc < 127) {
#pragma unroll
      for (int rep = 0; rep < 4; rep++) {
        int idx = rep * 256 + tid;
        *(bfx8*)&lk[cur ^ 1][idx >> 5][(idx & 31) * 8] = kreg[rep];
        *(bfx8*)&lvt[cur ^ 1][idx >> 2][(idx & 3) * 8] = vreg[rep];
      }
    }
    __syncthreads();              // single barrier: staged buffers visible for sc+1
  }

  // epilogue: add self term, normalize, scatter into concat[b,m,hh*256+d]
#pragma unroll
  for (int r = 0; r < 16; r++) {
    int row = (r & 3) + 8 * (r >> 2) + 4 * h;   // 0..31
    float ps = __shfl(ps_l, row);               // lane 'row' holds this row's ps
    float dinv = 1.f / (dacc[r] + ps);
    const __bf16* mvrow = mv + mbase + (long)row * 256;
    __bf16* crow = concat + ((long)(b * 1024 + mw + row)) * 2048 + hh * 256;
#pragma unroll
    for (int dt = 0; dt < 8; dt++) {
      int d = dt * 32 + l31;
      crow[d] = (__bf16)((oacc[dt][r] + ps * (float)mvrow[d]) * dinv);
    }
  }
}

// ---------------- LayerNorm over 4 f32 partials + residual ----------------
__global__ __launch_bounds__(256)
void ln4_kernel(const float* __restrict__ parts, const float* __restrict__ res,
                const float* __restrict__ g, const float* __restrict__ beta,
                __bf16* __restrict__ outb, float* __restrict__ outf) {
  int row  = blockIdx.x * 4 + (threadIdx.x >> 6);
  int lane = threadIdx.x & 63;
  const float* p = parts + (long)row * 256 + lane * 4;
  f32x4 a0 = *(const f32x4*)p;
  f32x4 a1 = *(const f32x4*)(p + 1048576);
  f32x4 a2 = *(const f32x4*)(p + 2097152);
  f32x4 a3 = *(const f32x4*)(p + 3145728);
  f32x4 rv = *(const f32x4*)(res + (long)row * 256 + lane * 4);
  float v[4], s1 = 0.f, s2 = 0.f;
#pragma unroll
  for (int i = 0; i < 4; i++) {
    v[i] = a0[i] + a1[i] + a2[i] + a3[i] + rv[i];
    s1 += v[i];
    s2 += v[i] * v[i];
  }
#pragma unroll
  for (int off = 32; off >= 1; off >>= 1) {
    s1 += __shfl_xor(s1, off);
    s2 += __shfl_xor(s2, off);
  }
  float mean = s1 * (1.f / 256.f);
  float var  = fmaxf(s2 * (1.f / 256.f) - mean * mean, 0.f);
  float rstd = rsqrtf(var + 1e-6f);
#pragma unroll
  for (int i = 0; i < 4; i++) {
    int c = lane * 4 + i;
    float o = (v[i] - mean) * rstd * g[c] + beta[c];
    if (outb) outb[(long)row * 256 + c] = (__bf16)o;
    if (outf) outf[(long)row * 256 + c] = o;
  }
}

extern "C" void kernel_launch(void* const* d_in, const int* in_sizes, int n_in,
                              void* d_out, int out_size, void* d_ws, size_t ws_size,
                              hipStream_t stream) {
  const float* state  = (const float*)d_in[0];
  const float* input  = (const float*)d_in[1];
  const float* Wk     = (const float*)d_in[2];
  const float* bk     = (const float*)d_in[3];
  const float* Wv     = (const float*)d_in[4];
  const float* bv     = (const float*)d_in[5];
  const float* Wq     = (const float*)d_in[6];
  const float* bq     = (const float*)d_in[7];
  const float* Wo     = (const float*)d_in[8];
  const float* bo     = (const float*)d_in[9];
  const float* ln1g   = (const float*)d_in[10];
  const float* ln1b   = (const float*)d_in[11];
  const float* W_in   = (const float*)d_in[12];
  const float* b_in   = (const float*)d_in[13];
  const float* Wg_nl  = (const float*)d_in[14];
  const float* bg_nl  = (const float*)d_in[15];
  const float* Wg_l   = (const float*)d_in[16];
  const float* bg_l   = (const float*)d_in[17];
  const float* Wg_o   = (const float*)d_in[18];
  const float* bg_o   = (const float*)d_in[19];
  const float* ln2g   = (const float*)d_in[20];
  const float* ln2b   = (const float*)d_in[21];
  float* out = (float*)d_out;

  const size_t needed_elems = 28442624;   // 56.9 MB, proven budget
  if (ws_size < needed_elems * sizeof(__bf16)) return;

  __bf16* ws = (__bf16*)d_ws;
  size_t off = 0;
  auto alloc = [&](size_t n) { __bf16* p = ws + off; off += n; return p; };
  __bf16* Wkvqt  = alloc(655360);    // [2560][256]: Wk^T | Wv^T | Wq^T(8)
  __bf16* Wot    = alloc(524288);    // [256][2048]
  __bf16* ik     = alloc(4194304);   // [16384][256]
  __bf16* ivT    = alloc(4194304);   // [4][128][256][32]
  __bf16* mk     = alloc(1048576);   // [4096][256]
  __bf16* mv     = alloc(1048576);
  __bf16* qbuf   = alloc(8388608);   // [8][4096][256]
  __bf16* concat = alloc(8388608);   // [4096][2048]
  // FFN/late-phase aliases over dead buffers
  float*  wo_parts = (float*)qbuf;           // f32[4][4096][256] (qbuf dead after attn)
  __bf16* x      = mv;                       // bf16 LN1 out
  __bf16* hbuf   = ik;                       // [4096][1024]
  __bf16* t12    = qbuf;                     // [4096][2048]
  float*  ff_parts = (float*)ik;             // f32[4][4096][256] over ik+ivT
  __bf16* Wffn   = concat;                   // FFN weights^T (2621440 el)
  float*  xf     = (float*)(concat + 3670016); // f32 residual [4096][256]

  dim3 blk(256);

  trans_attn_t<<<dim3(288), blk, 0, stream>>>(Wk, Wv, Wq, Wo, Wkvqt, Wot);

  // merged projections: K|V input (512 blocks) + K|V|Q state (640 blocks)
  proj2<<<dim3(1152), blk, 0, stream>>>(input, state, Wkvqt, bk, bv, bq,
                                        ik, ivT, mk, mv, qbuf);

  attn_kernel<<<dim3(8, 4, 8), blk, 0, stream>>>(qbuf, ik, ivT, mk, mv, concat);

  // Wo: split-K (4 x 512) -> f32 partials, 256 blocks
  gemm_bt<<<dim3(32, 2, 4), blk, 0, stream>>>(concat, nullptr, Wot, bo, nullptr, nullptr,
                                              nullptr, nullptr, nullptr, wo_parts,
                                              4096, 256, 2048, 512, 0, 7, 0);
  ln4_kernel<<<dim3(1024), blk, 0, stream>>>(wo_parts, state, ln1g, ln1b, x, xf);

  trans_ffn_t<<<dim3(640), blk, 0, stream>>>(W_in, Wg_nl, Wg_l, Wg_o, Wffn);

  gemm_bt<<<dim3(32, 8), blk, 0, stream>>>(x, nullptr, Wffn, b_in, nullptr, nullptr,
                                           hbuf, nullptr, nullptr, nullptr,
                                           4096, 1024, 256, 256, 0, 0, 1);
  // fused Wg_nl|Wg_l: N=2048, relu on first half
  gemm_bt<<<dim3(32, 16), blk, 0, stream>>>(hbuf, nullptr, Wffn + 262144, bg_nl, bg_l, nullptr,
                                            t12, nullptr, nullptr, nullptr,
                                            4096, 2048, 1024, 1024, 0, 6, 0);
  // Wg_o with gating fused into the stager: split-K (4 x 256) -> f32 partials
  gemm_bt<<<dim3(32, 2, 4), blk, 0, stream>>>(t12, nullptr, Wffn + 2359296, bg_o, nullptr, nullptr,
                                              nullptr, nullptr, nullptr, ff_parts,
                                              4096, 256, 1024, 256, 2, 7, 0);
  ln4_kernel<<<dim3(1024), blk, 0, stream>>>(ff_parts, xf, ln2g, ln2b, nullptr, out);
}